// Round 1
// 126.382 us; speedup vs baseline: 1.1434x; 1.1434x over previous
//
#include <hip/hip_runtime.h>

// FBSNN loss — recurrence broken via q-grid tabulation.
//
// Round 16: the 50-step sequential q-net scan (one latency-exposed wave,
// ~2900 cyc/step = ~62 of the 73 us) is replaced by:
//   Kernel A: tabulate q(t_n, y) on a 256-pt y-grid (Delta=1/8, nodes exact
//             in bf16) for all 50 timesteps IN PARALLEL (800 waves).
//   Kernel B: per block of 16 paths: load grid->LDS; wave 0 runs the scan
//             with Catmull-Rom interp (~200 cyc/step), publishing y rows
//             through an LDS release/acquire counter; 8 waves (2/SIMD,
//             latency mutually hidden) run the 51 Y-net+tangent evals as
//             rows become available; epilogue residuals + one atomicAdd.
// Residual f=q^2 uses interpolated q (error ~1e-4 << existing bf16 noise).

#define NPATH   4096
#define NSTEP   50
#define DT_F    0.02f
#define SQRT_DT 0.14142136f
#define SIGMA_F 0.5f
#define INV2PI  0.15915494309189535f
#define TWOPI_F 6.28318530717958648f

#define GRID_N   256
#define GRID_INV 8.0f
#define GRID_DY  0.125f

typedef __attribute__((ext_vector_type(8)))  short s16x8;
typedef __attribute__((ext_vector_type(4)))  float f32x4;
typedef __attribute__((ext_vector_type(4)))  float float4v;

#if __has_builtin(__builtin_amdgcn_cvt_pk_bf16_f32)
__device__ __forceinline__ unsigned pkbf(float a, float b) {
    auto r = __builtin_amdgcn_cvt_pk_bf16_f32(a, b);
    unsigned u; __builtin_memcpy(&u, &r, 4); return u;
}
#else
__device__ __forceinline__ unsigned pkbf(float a, float b) {
    unsigned ua = __float_as_uint(a), ub = __float_as_uint(b);
    ua += 0x7fffu + ((ua >> 16) & 1u);
    ub += 0x7fffu + ((ub >> 16) & 1u);
    return (ua >> 16) | (ub & 0xffff0000u);
}
#endif

__device__ __forceinline__ s16x8 frag4(unsigned a, unsigned b, unsigned c, unsigned d) {
    union { unsigned u[4]; s16x8 s; } x;
    x.u[0] = a; x.u[1] = b; x.u[2] = c; x.u[3] = d;
    return x.s;
}

__device__ __forceinline__ float sinrev(float x) {
#if __has_builtin(__builtin_amdgcn_sinf)
    return __builtin_amdgcn_sinf(x);
#else
    return __sinf(x * TWOPI_F);
#endif
}
__device__ __forceinline__ float cosrev(float x) {
#if __has_builtin(__builtin_amdgcn_cosf)
    return __builtin_amdgcn_cosf(x);
#else
    return __cosf(x * TWOPI_F);
#endif
}

__device__ __forceinline__ int slot16(int t, int r) {
    return (t < 2) ? 8 * (r >> 2) + 4 * t + (r & 3)
                   : 32 + 8 * (r >> 2) + 4 * (t - 2) + (r & 3);
}

struct NetFrags {
    s16x8 Ain[4];
    s16x8 AH[3][4][2];
    s16x8 Aout[2];
    f32x4 bIn[4];
    f32x4 bHd[3][4];
    float bout;
};

__device__ __forceinline__ void build_net(
    const float* __restrict__ Win, const float* __restrict__ bin,
    const float* __restrict__ Whid, const float* __restrict__ bhid,
    const float* __restrict__ Wout, const float* __restrict__ bo,
    int qd, int m, NetFrags& NF)
{
#pragma unroll
    for (int t = 0; t < 4; ++t) {
        const int uo = slot16(t, m);
        unsigned w0 = 0;
        if (qd == 0) w0 = pkbf(INV2PI * Win[uo], INV2PI * Win[64 + uo]);
        NF.Ain[t] = frag4(w0, 0u, 0u, 0u);
#pragma unroll
        for (int L = 0; L < 3; ++L) {
            const float* W = Whid + L * 4096 + uo;
#pragma unroll
            for (int kk = 0; kk < 2; ++kk) {
                unsigned w[4];
#pragma unroll
                for (int j2 = 0; j2 < 4; ++j2) {
                    int e0 = 32 * kk + 8 * qd + 2 * j2;
                    w[j2] = pkbf(INV2PI * W[e0 * 64], INV2PI * W[(e0 + 1) * 64]);
                }
                NF.AH[L][t][kk] = frag4(w[0], w[1], w[2], w[3]);
            }
        }
#pragma unroll
        for (int i = 0; i < 4; ++i) {
            const int u = slot16(t, 4 * qd + i);
            NF.bIn[t][i] = INV2PI * bin[u];
#pragma unroll
            for (int L = 0; L < 3; ++L)
                NF.bHd[L][t][i] = INV2PI * bhid[L * 64 + u];
        }
    }
#pragma unroll
    for (int kk = 0; kk < 2; ++kk) {
        unsigned w[4] = {0u, 0u, 0u, 0u};
        if (m == 0) {
#pragma unroll
            for (int j2 = 0; j2 < 4; ++j2) {
                int e0 = 32 * kk + 8 * qd + 2 * j2;
                w[j2] = pkbf(Wout[e0], Wout[e0 + 1]);
            }
        }
        NF.Aout[kk] = frag4(w[0], w[1], w[2], w[3]);
    }
    NF.bout = bo[0];
}

__device__ __forceinline__ void trans16(const f32x4* C, s16x8& B0, s16x8& B1) {
    float a[4][4];
#pragma unroll
    for (int t = 0; t < 4; ++t)
#pragma unroll
        for (int i = 0; i < 4; ++i) a[t][i] = sinrev(C[t][i]);
    B0 = frag4(pkbf(a[0][0], a[0][1]), pkbf(a[0][2], a[0][3]),
               pkbf(a[1][0], a[1][1]), pkbf(a[1][2], a[1][3]));
    B1 = frag4(pkbf(a[2][0], a[2][1]), pkbf(a[2][2], a[2][3]),
               pkbf(a[3][0], a[3][1]), pkbf(a[3][2], a[3][3]));
}

__device__ __forceinline__ void trans16t(const f32x4* Cf, const f32x4* Ct,
                                         s16x8& Bf0, s16x8& Bf1,
                                         s16x8& Bt0, s16x8& Bt1)
{
    float s[4][4], d[4][4];
#pragma unroll
    for (int t = 0; t < 4; ++t)
#pragma unroll
        for (int i = 0; i < 4; ++i) {
            float cf = Cf[t][i];
            s[t][i] = sinrev(cf);
            d[t][i] = cosrev(cf) * (TWOPI_F * Ct[t][i]);
        }
    Bf0 = frag4(pkbf(s[0][0], s[0][1]), pkbf(s[0][2], s[0][3]),
                pkbf(s[1][0], s[1][1]), pkbf(s[1][2], s[1][3]));
    Bf1 = frag4(pkbf(s[2][0], s[2][1]), pkbf(s[2][2], s[2][3]),
                pkbf(s[3][0], s[3][1]), pkbf(s[3][2], s[3][3]));
    Bt0 = frag4(pkbf(d[0][0], d[0][1]), pkbf(d[0][2], d[0][3]),
                pkbf(d[1][0], d[1][1]), pkbf(d[1][2], d[1][3]));
    Bt1 = frag4(pkbf(d[2][0], d[2][1]), pkbf(d[2][2], d[2][3]),
                pkbf(d[3][0], d[3][1]), pkbf(d[3][2], d[3][3]));
}

__device__ __forceinline__ void hidden_tan(const NetFrags& NF, int L,
    const f32x4& zc,
    const s16x8& Bf0, const s16x8& Bf1, const s16x8& Bt0, const s16x8& Bt1,
    f32x4* Cf, f32x4* Ct)
{
#pragma unroll
    for (int t = 0; t < 4; ++t) {
        f32x4 c = __builtin_amdgcn_mfma_f32_16x16x32_bf16(NF.AH[L][t][0], Bf0, NF.bHd[L][t], 0, 0, 0);
        Cf[t]   = __builtin_amdgcn_mfma_f32_16x16x32_bf16(NF.AH[L][t][1], Bf1, c, 0, 0, 0);
        f32x4 z = __builtin_amdgcn_mfma_f32_16x16x32_bf16(NF.AH[L][t][0], Bt0, zc, 0, 0, 0);
        Ct[t]   = __builtin_amdgcn_mfma_f32_16x16x32_bf16(NF.AH[L][t][1], Bt1, z, 0, 0, 0);
    }
}

__device__ __forceinline__ float grid_ylo(const float* __restrict__ y0p) {
    // identical expression in both kernels -> bitwise-identical ylo
    return floorf(y0p[0] * 8.0f) * 0.125f - 16.0f;
}

// q-net forward for one 16-col batch; result valid at qd==0 lanes, col m.
__device__ __forceinline__ float qnet16(const NetFrags& NF, const s16x8& Bty) {
    const f32x4 zc = {0.0f, 0.0f, 0.0f, 0.0f};
    f32x4 C[4];
#pragma unroll
    for (int t = 0; t < 4; ++t)
        C[t] = __builtin_amdgcn_mfma_f32_16x16x32_bf16(NF.Ain[t], Bty, NF.bIn[t], 0, 0, 0);
    s16x8 B0, B1;
    trans16(C, B0, B1);
#pragma unroll
    for (int L = 0; L < 3; ++L) {
#pragma unroll
        for (int t = 0; t < 4; ++t) {
            f32x4 c = __builtin_amdgcn_mfma_f32_16x16x32_bf16(NF.AH[L][t][0], B0, NF.bHd[L][t], 0, 0, 0);
            C[t]    = __builtin_amdgcn_mfma_f32_16x16x32_bf16(NF.AH[L][t][1], B1, c, 0, 0, 0);
        }
        trans16(C, B0, B1);
    }
    f32x4 Co = __builtin_amdgcn_mfma_f32_16x16x32_bf16(NF.Aout[0], B0, zc, 0, 0, 0);
    Co = __builtin_amdgcn_mfma_f32_16x16x32_bf16(NF.Aout[1], B1, Co, 0, 0, 0);
    return Co[0] + NF.bout;
}

// ================= kernel A: q-grid tabulation (fully parallel) ==========

extern "C" __global__ void __launch_bounds__(256, 1)
fbsnn_qgrid(const float* __restrict__ q_Win, const float* __restrict__ q_bin,
            const float* __restrict__ q_Whid, const float* __restrict__ q_bhid,
            const float* __restrict__ q_Wout, const float* __restrict__ q_bout,
            const float* __restrict__ y0p, float* __restrict__ qgrid)
{
    const int tid = (int)threadIdx.x;
    const int wv  = tid >> 6;
    const int l   = tid & 63;
    const int qd  = l >> 4;
    const int m   = l & 15;
    const int gid = (int)blockIdx.x * 4 + wv;   // 0..799 (200 blocks x 4 waves)
    const int n   = gid >> 4;                   // timestep 0..49
    const int gb  = (gid & 15) << 4;            // grid col base

    NetFrags NF;
    build_net(q_Win, q_bin, q_Whid, q_bhid, q_Wout, q_bout, qd, m, NF);

    const float ylo = grid_ylo(y0p);
    const float tt  = n * DT_F;
    const float yg  = ylo + (float)(gb + m) * GRID_DY;   // node = k/8: exact bf16
    const s16x8 Bty = frag4((qd == 0) ? pkbf(tt, yg) : 0u, 0u, 0u, 0u);

    const float q = qnet16(NF, Bty);
    if (qd == 0) qgrid[n * GRID_N + gb + m] = q;
}

// ================= kernel B: scan + Y-evals + residuals ==================

extern "C" __global__ void __launch_bounds__(512, 2)
fbsnn_main(const float* __restrict__ Y_Win, const float* __restrict__ Y_bin,
           const float* __restrict__ Y_Whid, const float* __restrict__ Y_bhid,
           const float* __restrict__ Y_Wout, const float* __restrict__ Y_bout,
           const float* __restrict__ y0p, const float* __restrict__ dW,
           const float* __restrict__ qgrid_g, float* __restrict__ out)
{
    __shared__ __align__(16) float qg[NSTEP * GRID_N];   // 51200 B
    __shared__ float yb[51 * 16];
    __shared__ float qb[50 * 16];
    __shared__ float Yb[51 * 16];
    __shared__ float dYb[51 * 16];
    __shared__ float partial[8];
    __shared__ int   prog;

    const int tid = (int)threadIdx.x;
    const int wv  = tid >> 6;          // 0..7; wave 0 = scanner
    const int l   = tid & 63;
    const int qd  = l >> 4;
    const int m   = l & 15;
    const int p   = (int)blockIdx.x * 16 + m;

    if (tid == 0) prog = 0;

    // ---- stage 0: q-grid -> LDS (3200 x 16B chunks, 512 threads) ----
    {
        float4v tmp[7];
#pragma unroll
        for (int k = 0; k < 7; ++k) {
            const int idx = tid + k * 512;
            if (idx < 3200) tmp[k] = ((const float4v*)qgrid_g)[idx];
        }
#pragma unroll
        for (int k = 0; k < 7; ++k) {
            const int idx = tid + k * 512;
            if (idx < 3200) ((float4v*)qg)[idx] = tmp[k];
        }
    }
    __syncthreads();

    const f32x4 zc  = {0.0f, 0.0f, 0.0f, 0.0f};
    const float ylo = grid_ylo(y0p);

    if (wv == 0) {
        // ---- stage 1: trivial scan with Catmull-Rom interp, publish rows ----
        float y = y0p[0];
        float dw_cur = dW[p];
        for (int n = 0; n < NSTEP; ++n) {
            if (l < 16) yb[n * 16 + m] = y;
            __threadfence_block();
            if (l == 0) __hip_atomic_store(&prog, n + 1, __ATOMIC_RELEASE,
                                           __HIP_MEMORY_SCOPE_WORKGROUP);
            const int n1 = (n + 1 < NSTEP) ? n + 1 : NSTEP - 1;
            const float dw_next = dW[n1 * NPATH + p];

            float u = (y - ylo) * GRID_INV;
            u = fminf(fmaxf(u, 1.0f), 253.999f);
            int i = (int)u;                      // u >= 1 -> trunc == floor
            if (i > 253) i = 253;
            const float fr = u - (float)i;
            const float* row = qg + n * GRID_N + i;
            const float q0 = row[-1], q1 = row[0], q2 = row[1], q3 = row[2];
            const float qt = q1 + 0.5f * fr * ((q2 - q0)
                           + fr * ((2.0f * q0 - 5.0f * q1 + 4.0f * q2 - q3)
                           + fr * (3.0f * (q1 - q2) + q3 - q0)));

            if (l < 16) qb[n * 16 + m] = qt;
            y = fmaf(qt, DT_F, y) + SIGMA_F * (dw_cur * SQRT_DT);
            dw_cur = dw_next;
        }
        if (l < 16) yb[NSTEP * 16 + m] = y;
        __threadfence_block();
        if (l == 0) __hip_atomic_store(&prog, NSTEP + 1, __ATOMIC_RELEASE,
                                       __HIP_MEMORY_SCOPE_WORKGROUP);
    }

    // ---- stage 2: Y-net + tangent evals, 51 rows over 8 waves ----
    // wave 0 (after its scan): n = 46..50 (5). waves 1..4: 7 each, 5..7: 6
    // each, n = (wv-1) + 7*i  -> covers 0..45 exactly once.
    NetFrags NF;
    build_net(Y_Win, Y_bin, Y_Whid, Y_bhid, Y_Wout, Y_bout, qd, m, NF);
    const s16x8 Btn = frag4((qd == 0) ? pkbf(0.0f, 1.0f) : 0u, 0u, 0u, 0u);

    const int cnt = (wv == 0) ? 5 : ((wv <= 4) ? 7 : 6);
    for (int i = 0; i < cnt; ++i) {
        const int k = (wv == 0) ? (46 + i) : ((wv - 1) + 7 * i);

        while (__hip_atomic_load(&prog, __ATOMIC_ACQUIRE,
                                 __HIP_MEMORY_SCOPE_WORKGROUP) <= k)
            __builtin_amdgcn_s_sleep(2);

        const float yv = yb[k * 16 + m];
        const float tt = k * DT_F;
        const s16x8 Bty = frag4((qd == 0) ? pkbf(tt, yv) : 0u, 0u, 0u, 0u);

        f32x4 Cf[4], Ct[4];
#pragma unroll
        for (int t = 0; t < 4; ++t) {
            Cf[t] = __builtin_amdgcn_mfma_f32_16x16x32_bf16(NF.Ain[t], Bty, NF.bIn[t], 0, 0, 0);
            Ct[t] = __builtin_amdgcn_mfma_f32_16x16x32_bf16(NF.Ain[t], Btn, zc, 0, 0, 0);
        }
        s16x8 bf0, bf1, bt0, bt1;
        trans16t(Cf, Ct, bf0, bf1, bt0, bt1);

#pragma unroll
        for (int L = 0; L < 3; ++L) {
            hidden_tan(NF, L, zc, bf0, bf1, bt0, bt1, Cf, Ct);
            trans16t(Cf, Ct, bf0, bf1, bt0, bt1);
        }

        f32x4 Cof = __builtin_amdgcn_mfma_f32_16x16x32_bf16(NF.Aout[0], bf0, zc, 0, 0, 0);
        Cof = __builtin_amdgcn_mfma_f32_16x16x32_bf16(NF.Aout[1], bf1, Cof, 0, 0, 0);
        f32x4 Cot = __builtin_amdgcn_mfma_f32_16x16x32_bf16(NF.Aout[0], bt0, zc, 0, 0, 0);
        Cot = __builtin_amdgcn_mfma_f32_16x16x32_bf16(NF.Aout[1], bt1, Cot, 0, 0, 0);

        if (qd == 0) {
            Yb[k * 16 + m]  = Cof[0] + NF.bout;
            dYb[k * 16 + m] = Cot[0];
        }
    }

    // ---- epilogue: residuals + reduction ----
    __syncthreads();

    float acc = 0.0f;
    for (int it = tid; it < 816; it += 512) {
        if (it < 800) {
            const int n  = it >> 4;
            const int pp = it & 15;
            const float q    = qb[it];
            const float dYc  = dYb[it];
            const float Yn   = Yb[it];
            const float Yn1  = Yb[it + 16];
            const float dws  = dW[n * NPATH + (int)blockIdx.x * 16 + pp] * SQRT_DT;
            const float Ytil = fmaf(-q * q, DT_F, Yn) + (SIGMA_F * dYc) * dws;
            const float r    = Yn1 - Ytil;
            acc = fmaf(r, r, acc);
        } else {
            const int pp = it - 800;
            const float y50  = yb[NSTEP * 16 + pp];
            const float Y50  = Yb[NSTEP * 16 + pp];
            const float dY50 = dYb[NSTEP * 16 + pp];
            const float r1 = Y50 - y50 * y50;
            const float r2 = dY50 - 2.0f * y50;
            acc = fmaf(r1, r1, fmaf(r2, r2, acc));
        }
    }
#pragma unroll
    for (int off = 32; off > 0; off >>= 1) acc += __shfl_down(acc, off, 64);
    if (l == 0) partial[wv] = acc;
    __syncthreads();
    if (tid == 0) {
        float s = partial[0] + partial[1] + partial[2] + partial[3]
                + partial[4] + partial[5] + partial[6] + partial[7];
        atomicAdd(out, s * (1.0f / (float)NPATH));
    }
}

// ================= host launch =================

extern "C" void kernel_launch(void* const* d_in, const int* in_sizes, int n_in,
                              void* d_out, int out_size, void* d_ws, size_t ws_size,
                              hipStream_t stream)
{
    const float* Y_Win  = (const float*)d_in[0];
    const float* Y_bin  = (const float*)d_in[1];
    const float* Y_Whid = (const float*)d_in[2];
    const float* Y_bhid = (const float*)d_in[3];
    const float* Y_Wout = (const float*)d_in[4];
    const float* Y_bout = (const float*)d_in[5];
    const float* q_Win  = (const float*)d_in[6];
    const float* q_bin  = (const float*)d_in[7];
    const float* q_Whid = (const float*)d_in[8];
    const float* q_bhid = (const float*)d_in[9];
    const float* q_Wout = (const float*)d_in[10];
    const float* q_bout = (const float*)d_in[11];
    const float* y0p    = (const float*)d_in[12];
    const float* dW     = (const float*)d_in[13];

    float* qgrid = (float*)d_ws;   // 50 * 256 * 4 = 51,200 B

    hipMemsetAsync(d_out, 0, sizeof(float), stream);

    fbsnn_qgrid<<<dim3(200), dim3(256), 0, stream>>>(
        q_Win, q_bin, q_Whid, q_bhid, q_Wout, q_bout, y0p, qgrid);

    fbsnn_main<<<dim3(NPATH / 16), dim3(512), 0, stream>>>(
        Y_Win, Y_bin, Y_Whid, Y_bhid, Y_Wout, Y_bout,
        y0p, dW, qgrid, (float*)d_out);
}

// Round 2
// 118.066 us; speedup vs baseline: 1.2239x; 1.0704x over previous
//
#include <hip/hip_runtime.h>

// FBSNN loss — q-grid tabulation + prepacked net fragments + 16-wave main.
//
// Round 17:
//   Kernel A (fbsnn_prep, 101 blocks x 256 thr):
//     blocks 0..99: q(t_n, y) on the 256-pt y-grid, 2 ILP-interleaved evals
//                   per wave (build_net amortized, chains overlapped).
//     block 100 wave 0: builds Y-net fragments once and stores them packed
//                   [frag][lane] to workspace (48128 B after the 51200 B grid).
//   Kernel B (fbsnn_main, 256 blocks x 1024 thr, 112 KB dynamic LDS):
//     stage 0: block-copy qgrid+frags ws->LDS (coalesced float4).
//     wave 0: 50-step scan with Catmull-Rom interp (~200 cyc/step), publishes
//             y rows via LDS release/acquire counter; does NO evals.
//     waves 1..15: 51 Y-net+tangent evals (rows (wv-1)+15j; waves 1..6 also
//             take rows 45..50), 4 waves/SIMD, MFMA operands via
//             conflict-free ds_read_b128 from the packed-frag LDS block.
//     epilogue: residuals + one atomicAdd per block.
// Same math as r16 (identical build_net / interp / eval) -> same absmax.

#define NPATH   4096
#define NSTEP   50
#define DT_F    0.02f
#define SQRT_DT 0.14142136f
#define SIGMA_F 0.5f
#define INV2PI  0.15915494309189535f
#define TWOPI_F 6.28318530717958648f

#define GRID_N   256
#define GRID_INV 8.0f
#define GRID_DY  0.125f

#define QG_FLOATS  (NSTEP * GRID_N)        // 12800
#define NFRAG      47
#define FRAG_FLOATS (NFRAG * 64 * 4)       // 12032

// fragment ids (16B per lane each)
#define FR_AIN(t)     (t)                          // 0..3
#define FR_AH(L,t,kk) (4 + (L)*8 + (t)*2 + (kk))   // 4..27
#define FR_AOUT(kk)   (28 + (kk))                  // 28..29
#define FR_BIN(t)     (30 + (t))                   // 30..33
#define FR_BHD(L,t)   (34 + (L)*4 + (t))           // 34..45
#define FR_BOUT       46

// main-kernel LDS layout (float offsets)
#define L_QG    0
#define L_FR    QG_FLOATS                  // 12800
#define L_YB    (L_FR + FRAG_FLOATS)       // 24832  (51*16)
#define L_QB    (L_YB + 816)               // 25648  (50*16)
#define L_YY    (L_QB + 800)               // 26448  (51*16)
#define L_DY    (L_YY + 816)               // 27264  (51*16)
#define L_PART  (L_DY + 816)               // 28080  (16)
#define L_PROG  (L_PART + 16)              // 28096
#define SMEM_FLOATS (L_PROG + 4)
#define SMEM_BYTES  (SMEM_FLOATS * 4)      // 112,400 B

typedef __attribute__((ext_vector_type(8)))  short s16x8;
typedef __attribute__((ext_vector_type(4)))  float f32x4;
typedef __attribute__((ext_vector_type(4)))  float float4v;

#if __has_builtin(__builtin_amdgcn_cvt_pk_bf16_f32)
__device__ __forceinline__ unsigned pkbf(float a, float b) {
    auto r = __builtin_amdgcn_cvt_pk_bf16_f32(a, b);
    unsigned u; __builtin_memcpy(&u, &r, 4); return u;
}
#else
__device__ __forceinline__ unsigned pkbf(float a, float b) {
    unsigned ua = __float_as_uint(a), ub = __float_as_uint(b);
    ua += 0x7fffu + ((ua >> 16) & 1u);
    ub += 0x7fffu + ((ub >> 16) & 1u);
    return (ua >> 16) | (ub & 0xffff0000u);
}
#endif

__device__ __forceinline__ s16x8 frag4(unsigned a, unsigned b, unsigned c, unsigned d) {
    union { unsigned u[4]; s16x8 s; } x;
    x.u[0] = a; x.u[1] = b; x.u[2] = c; x.u[3] = d;
    return x.s;
}

__device__ __forceinline__ float sinrev(float x) {
#if __has_builtin(__builtin_amdgcn_sinf)
    return __builtin_amdgcn_sinf(x);
#else
    return __sinf(x * TWOPI_F);
#endif
}
__device__ __forceinline__ float cosrev(float x) {
#if __has_builtin(__builtin_amdgcn_cosf)
    return __builtin_amdgcn_cosf(x);
#else
    return __cosf(x * TWOPI_F);
#endif
}

__device__ __forceinline__ int slot16(int t, int r) {
    return (t < 2) ? 8 * (r >> 2) + 4 * t + (r & 3)
                   : 32 + 8 * (r >> 2) + 4 * (t - 2) + (r & 3);
}

struct NetFrags {
    s16x8 Ain[4];
    s16x8 AH[3][4][2];
    s16x8 Aout[2];
    f32x4 bIn[4];
    f32x4 bHd[3][4];
    float bout;
};

__device__ __forceinline__ void build_net(
    const float* __restrict__ Win, const float* __restrict__ bin,
    const float* __restrict__ Whid, const float* __restrict__ bhid,
    const float* __restrict__ Wout, const float* __restrict__ bo,
    int qd, int m, NetFrags& NF)
{
#pragma unroll
    for (int t = 0; t < 4; ++t) {
        const int uo = slot16(t, m);
        unsigned w0 = 0;
        if (qd == 0) w0 = pkbf(INV2PI * Win[uo], INV2PI * Win[64 + uo]);
        NF.Ain[t] = frag4(w0, 0u, 0u, 0u);
#pragma unroll
        for (int L = 0; L < 3; ++L) {
            const float* W = Whid + L * 4096 + uo;
#pragma unroll
            for (int kk = 0; kk < 2; ++kk) {
                unsigned w[4];
#pragma unroll
                for (int j2 = 0; j2 < 4; ++j2) {
                    int e0 = 32 * kk + 8 * qd + 2 * j2;
                    w[j2] = pkbf(INV2PI * W[e0 * 64], INV2PI * W[(e0 + 1) * 64]);
                }
                NF.AH[L][t][kk] = frag4(w[0], w[1], w[2], w[3]);
            }
        }
#pragma unroll
        for (int i = 0; i < 4; ++i) {
            const int u = slot16(t, 4 * qd + i);
            NF.bIn[t][i] = INV2PI * bin[u];
#pragma unroll
            for (int L = 0; L < 3; ++L)
                NF.bHd[L][t][i] = INV2PI * bhid[L * 64 + u];
        }
    }
#pragma unroll
    for (int kk = 0; kk < 2; ++kk) {
        unsigned w[4] = {0u, 0u, 0u, 0u};
        if (m == 0) {
#pragma unroll
            for (int j2 = 0; j2 < 4; ++j2) {
                int e0 = 32 * kk + 8 * qd + 2 * j2;
                w[j2] = pkbf(Wout[e0], Wout[e0 + 1]);
            }
        }
        NF.Aout[kk] = frag4(w[0], w[1], w[2], w[3]);
    }
    NF.bout = bo[0];
}

__device__ __forceinline__ void trans16(const f32x4* C, s16x8& B0, s16x8& B1) {
    float a[4][4];
#pragma unroll
    for (int t = 0; t < 4; ++t)
#pragma unroll
        for (int i = 0; i < 4; ++i) a[t][i] = sinrev(C[t][i]);
    B0 = frag4(pkbf(a[0][0], a[0][1]), pkbf(a[0][2], a[0][3]),
               pkbf(a[1][0], a[1][1]), pkbf(a[1][2], a[1][3]));
    B1 = frag4(pkbf(a[2][0], a[2][1]), pkbf(a[2][2], a[2][3]),
               pkbf(a[3][0], a[3][1]), pkbf(a[3][2], a[3][3]));
}

__device__ __forceinline__ void trans16t(const f32x4* Cf, const f32x4* Ct,
                                         s16x8& Bf0, s16x8& Bf1,
                                         s16x8& Bt0, s16x8& Bt1)
{
    float s[4][4], d[4][4];
#pragma unroll
    for (int t = 0; t < 4; ++t)
#pragma unroll
        for (int i = 0; i < 4; ++i) {
            float cf = Cf[t][i];
            s[t][i] = sinrev(cf);
            d[t][i] = cosrev(cf) * (TWOPI_F * Ct[t][i]);
        }
    Bf0 = frag4(pkbf(s[0][0], s[0][1]), pkbf(s[0][2], s[0][3]),
                pkbf(s[1][0], s[1][1]), pkbf(s[1][2], s[1][3]));
    Bf1 = frag4(pkbf(s[2][0], s[2][1]), pkbf(s[2][2], s[2][3]),
                pkbf(s[3][0], s[3][1]), pkbf(s[3][2], s[3][3]));
    Bt0 = frag4(pkbf(d[0][0], d[0][1]), pkbf(d[0][2], d[0][3]),
                pkbf(d[1][0], d[1][1]), pkbf(d[1][2], d[1][3]));
    Bt1 = frag4(pkbf(d[2][0], d[2][1]), pkbf(d[2][2], d[2][3]),
                pkbf(d[3][0], d[3][1]), pkbf(d[3][2], d[3][3]));
}

__device__ __forceinline__ float grid_ylo(const float* __restrict__ y0p) {
    return floorf(y0p[0] * 8.0f) * 0.125f - 16.0f;
}

// ============ kernel A: q-grid (2-wide ILP) + Y-frag prepack ============

extern "C" __global__ void __launch_bounds__(256, 1)
fbsnn_prep(const float* __restrict__ Y_Win, const float* __restrict__ Y_bin,
           const float* __restrict__ Y_Whid, const float* __restrict__ Y_bhid,
           const float* __restrict__ Y_Wout, const float* __restrict__ Y_bout,
           const float* __restrict__ q_Win, const float* __restrict__ q_bin,
           const float* __restrict__ q_Whid, const float* __restrict__ q_bhid,
           const float* __restrict__ q_Wout, const float* __restrict__ q_bout,
           const float* __restrict__ y0p, float* __restrict__ ws)
{
    const int tid = (int)threadIdx.x;
    const int wv  = tid >> 6;
    const int l   = tid & 63;
    const int qd  = l >> 4;
    const int m   = l & 15;
    const int blk = (int)blockIdx.x;

    if (blk == 100) {
        // ---- Y-net fragment prepack (wave 0 only) ----
        if (wv != 0) return;
        NetFrags NF;
        build_net(Y_Win, Y_bin, Y_Whid, Y_bhid, Y_Wout, Y_bout, qd, m, NF);
        float* wf = ws + QG_FLOATS;
#pragma unroll
        for (int t = 0; t < 4; ++t)
            *reinterpret_cast<s16x8*>(wf + (FR_AIN(t) * 64 + l) * 4) = NF.Ain[t];
#pragma unroll
        for (int L = 0; L < 3; ++L)
#pragma unroll
            for (int t = 0; t < 4; ++t)
#pragma unroll
                for (int kk = 0; kk < 2; ++kk)
                    *reinterpret_cast<s16x8*>(wf + (FR_AH(L, t, kk) * 64 + l) * 4) = NF.AH[L][t][kk];
#pragma unroll
        for (int kk = 0; kk < 2; ++kk)
            *reinterpret_cast<s16x8*>(wf + (FR_AOUT(kk) * 64 + l) * 4) = NF.Aout[kk];
#pragma unroll
        for (int t = 0; t < 4; ++t)
            *reinterpret_cast<f32x4*>(wf + (FR_BIN(t) * 64 + l) * 4) = NF.bIn[t];
#pragma unroll
        for (int L = 0; L < 3; ++L)
#pragma unroll
            for (int t = 0; t < 4; ++t)
                *reinterpret_cast<f32x4*>(wf + (FR_BHD(L, t) * 64 + l) * 4) = NF.bHd[L][t];
        f32x4 bo4 = {NF.bout, 0.0f, 0.0f, 0.0f};
        *reinterpret_cast<f32x4*>(wf + (FR_BOUT * 64 + l) * 4) = bo4;
        return;
    }

    // ---- q-grid: timestep n = blk>>1, columns 128*(blk&1) + 32*wv + 16*e ----
    NetFrags NF;
    build_net(q_Win, q_bin, q_Whid, q_bhid, q_Wout, q_bout, qd, m, NF);

    const int   n    = blk >> 1;
    const int   half = blk & 1;
    const float tt   = n * DT_F;
    const float ylo  = grid_ylo(y0p);
    const f32x4 zc   = {0.0f, 0.0f, 0.0f, 0.0f};

    s16x8 Bty[2];
#pragma unroll
    for (int e = 0; e < 2; ++e) {
        const int col = 128 * half + 32 * wv + 16 * e + m;
        const float yg = ylo + (float)col * GRID_DY;   // node = k/8: exact bf16
        Bty[e] = frag4((qd == 0) ? pkbf(tt, yg) : 0u, 0u, 0u, 0u);
    }

    f32x4 C[2][4];
#pragma unroll
    for (int e = 0; e < 2; ++e)
#pragma unroll
        for (int t = 0; t < 4; ++t)
            C[e][t] = __builtin_amdgcn_mfma_f32_16x16x32_bf16(NF.Ain[t], Bty[e], NF.bIn[t], 0, 0, 0);

    s16x8 B0[2], B1[2];
#pragma unroll
    for (int e = 0; e < 2; ++e) trans16(C[e], B0[e], B1[e]);

#pragma unroll
    for (int L = 0; L < 3; ++L) {
#pragma unroll
        for (int e = 0; e < 2; ++e)
#pragma unroll
            for (int t = 0; t < 4; ++t) {
                f32x4 c = __builtin_amdgcn_mfma_f32_16x16x32_bf16(NF.AH[L][t][0], B0[e], NF.bHd[L][t], 0, 0, 0);
                C[e][t] = __builtin_amdgcn_mfma_f32_16x16x32_bf16(NF.AH[L][t][1], B1[e], c, 0, 0, 0);
            }
#pragma unroll
        for (int e = 0; e < 2; ++e) trans16(C[e], B0[e], B1[e]);
    }

#pragma unroll
    for (int e = 0; e < 2; ++e) {
        f32x4 Co = __builtin_amdgcn_mfma_f32_16x16x32_bf16(NF.Aout[0], B0[e], zc, 0, 0, 0);
        Co = __builtin_amdgcn_mfma_f32_16x16x32_bf16(NF.Aout[1], B1[e], Co, 0, 0, 0);
        if (qd == 0)
            ws[n * GRID_N + 128 * half + 32 * wv + 16 * e + m] = Co[0] + NF.bout;
    }
}

// ============ kernel B: scan + Y-evals + residuals (16 waves) ============

extern "C" __global__ void __launch_bounds__(1024, 4)
fbsnn_main(const float* __restrict__ y0p, const float* __restrict__ dW,
           const float* __restrict__ ws, float* __restrict__ out)
{
    extern __shared__ __align__(16) float sf[];
    float* qg   = sf + L_QG;
    float* yb   = sf + L_YB;
    float* qb   = sf + L_QB;
    float* Yb   = sf + L_YY;
    float* dYb  = sf + L_DY;
    float* part = sf + L_PART;
    int*   prog = (int*)(sf + L_PROG);
    const char* fb = (const char*)(sf + L_FR);

    const int tid = (int)threadIdx.x;
    const int wv  = tid >> 6;          // 0..15; wave 0 = scanner
    const int l   = tid & 63;
    const int qd  = l >> 4;
    const int m   = l & 15;
    const int p   = (int)blockIdx.x * 16 + m;

    if (tid == 0) *prog = 0;

    // ---- stage 0: qgrid + packed frags -> LDS (6208 x 16B, coalesced) ----
    {
        float4v tmp[7];
#pragma unroll
        for (int k = 0; k < 7; ++k) {
            const int idx = tid + k * 1024;
            if (idx < 6208) tmp[k] = ((const float4v*)ws)[idx];
        }
#pragma unroll
        for (int k = 0; k < 7; ++k) {
            const int idx = tid + k * 1024;
            if (idx < 6208) ((float4v*)sf)[idx] = tmp[k];
        }
    }
    __syncthreads();

    const f32x4 zc  = {0.0f, 0.0f, 0.0f, 0.0f};
    const float ylo = grid_ylo(y0p);

    if (wv == 0) {
        // ---- scan: Catmull-Rom interp on the q-grid, publish rows ----
        float y = y0p[0];
        float dw_cur = dW[p];
        for (int n = 0; n < NSTEP; ++n) {
            if (l < 16) yb[n * 16 + m] = y;
            __threadfence_block();
            if (l == 0) __hip_atomic_store(prog, n + 1, __ATOMIC_RELEASE,
                                           __HIP_MEMORY_SCOPE_WORKGROUP);
            const int n1 = (n + 1 < NSTEP) ? n + 1 : NSTEP - 1;
            const float dw_next = dW[n1 * NPATH + p];

            float u = (y - ylo) * GRID_INV;
            u = fminf(fmaxf(u, 1.0f), 253.999f);
            int i = (int)u;
            if (i > 253) i = 253;
            const float fr = u - (float)i;
            const float* row = qg + n * GRID_N + i;
            const float q0 = row[-1], q1 = row[0], q2 = row[1], q3 = row[2];
            const float qt = q1 + 0.5f * fr * ((q2 - q0)
                           + fr * ((2.0f * q0 - 5.0f * q1 + 4.0f * q2 - q3)
                           + fr * (3.0f * (q1 - q2) + q3 - q0)));

            if (l < 16) qb[n * 16 + m] = qt;
            y = fmaf(qt, DT_F, y) + SIGMA_F * (dw_cur * SQRT_DT);
            dw_cur = dw_next;
        }
        if (l < 16) yb[NSTEP * 16 + m] = y;
        __threadfence_block();
        if (l == 0) __hip_atomic_store(prog, NSTEP + 1, __ATOMIC_RELEASE,
                                       __HIP_MEMORY_SCOPE_WORKGROUP);
    } else {
        // ---- consumers: rows (wv-1)+15j, j=0..2; waves 1..6 add 44+wv ----
        const s16x8 Btn = frag4((qd == 0) ? pkbf(0.0f, 1.0f) : 0u, 0u, 0u, 0u);
        const float boutY = *reinterpret_cast<const float*>(fb + (FR_BOUT * 64 + l) * 16);

        const int cnt = (wv <= 6) ? 4 : 3;
        for (int j = 0; j < cnt; ++j) {
            const int k = (j < 3) ? (wv - 1) + 15 * j : 44 + wv;

            while (__hip_atomic_load(prog, __ATOMIC_ACQUIRE,
                                     __HIP_MEMORY_SCOPE_WORKGROUP) <= k)
                __builtin_amdgcn_s_sleep(2);

            const float yv = yb[k * 16 + m];
            const float tt = k * DT_F;
            const s16x8 Bty = frag4((qd == 0) ? pkbf(tt, yv) : 0u, 0u, 0u, 0u);

            f32x4 Cf[4], Ct[4];
#pragma unroll
            for (int t = 0; t < 4; ++t) {
                const s16x8 a  = *reinterpret_cast<const s16x8*>(fb + (FR_AIN(t) * 64 + l) * 16);
                const f32x4 bi = *reinterpret_cast<const f32x4*>(fb + (FR_BIN(t) * 64 + l) * 16);
                Cf[t] = __builtin_amdgcn_mfma_f32_16x16x32_bf16(a, Bty, bi, 0, 0, 0);
                Ct[t] = __builtin_amdgcn_mfma_f32_16x16x32_bf16(a, Btn, zc, 0, 0, 0);
            }
            s16x8 bf0, bf1, bt0, bt1;
            trans16t(Cf, Ct, bf0, bf1, bt0, bt1);

#pragma unroll
            for (int L = 0; L < 3; ++L) {
#pragma unroll
                for (int t = 0; t < 4; ++t) {
                    const s16x8 a0 = *reinterpret_cast<const s16x8*>(fb + (FR_AH(L, t, 0) * 64 + l) * 16);
                    const s16x8 a1 = *reinterpret_cast<const s16x8*>(fb + (FR_AH(L, t, 1) * 64 + l) * 16);
                    const f32x4 bh = *reinterpret_cast<const f32x4*>(fb + (FR_BHD(L, t) * 64 + l) * 16);
                    f32x4 c = __builtin_amdgcn_mfma_f32_16x16x32_bf16(a0, bf0, bh, 0, 0, 0);
                    Cf[t]   = __builtin_amdgcn_mfma_f32_16x16x32_bf16(a1, bf1, c, 0, 0, 0);
                    f32x4 z = __builtin_amdgcn_mfma_f32_16x16x32_bf16(a0, bt0, zc, 0, 0, 0);
                    Ct[t]   = __builtin_amdgcn_mfma_f32_16x16x32_bf16(a1, bt1, z, 0, 0, 0);
                }
                trans16t(Cf, Ct, bf0, bf1, bt0, bt1);
            }

            const s16x8 o0 = *reinterpret_cast<const s16x8*>(fb + (FR_AOUT(0) * 64 + l) * 16);
            const s16x8 o1 = *reinterpret_cast<const s16x8*>(fb + (FR_AOUT(1) * 64 + l) * 16);
            f32x4 Cof = __builtin_amdgcn_mfma_f32_16x16x32_bf16(o0, bf0, zc, 0, 0, 0);
            Cof = __builtin_amdgcn_mfma_f32_16x16x32_bf16(o1, bf1, Cof, 0, 0, 0);
            f32x4 Cot = __builtin_amdgcn_mfma_f32_16x16x32_bf16(o0, bt0, zc, 0, 0, 0);
            Cot = __builtin_amdgcn_mfma_f32_16x16x32_bf16(o1, bt1, Cot, 0, 0, 0);

            if (qd == 0) {
                Yb[k * 16 + m]  = Cof[0] + boutY;
                dYb[k * 16 + m] = Cot[0];
            }
        }
    }

    // ---- epilogue: residuals + reduction ----
    __syncthreads();

    float acc = 0.0f;
    if (tid < 816) {
        const int it = tid;
        if (it < 800) {
            const int n  = it >> 4;
            const int pp = it & 15;
            const float q    = qb[it];
            const float dYc  = dYb[it];
            const float Yn   = Yb[it];
            const float Yn1  = Yb[it + 16];
            const float dws  = dW[n * NPATH + (int)blockIdx.x * 16 + pp] * SQRT_DT;
            const float Ytil = fmaf(-q * q, DT_F, Yn) + (SIGMA_F * dYc) * dws;
            const float r    = Yn1 - Ytil;
            acc = fmaf(r, r, acc);
        } else {
            const int pp = it - 800;
            const float y50  = yb[NSTEP * 16 + pp];
            const float Y50  = Yb[NSTEP * 16 + pp];
            const float dY50 = dYb[NSTEP * 16 + pp];
            const float r1 = Y50 - y50 * y50;
            const float r2 = dY50 - 2.0f * y50;
            acc = fmaf(r1, r1, fmaf(r2, r2, acc));
        }
    }
#pragma unroll
    for (int off = 32; off > 0; off >>= 1) acc += __shfl_down(acc, off, 64);
    if (l == 0) part[wv] = acc;
    __syncthreads();
    if (tid == 0) {
        float s = 0.0f;
#pragma unroll
        for (int w = 0; w < 16; ++w) s += part[w];
        atomicAdd(out, s * (1.0f / (float)NPATH));
    }
}

// ================= host launch =================

extern "C" void kernel_launch(void* const* d_in, const int* in_sizes, int n_in,
                              void* d_out, int out_size, void* d_ws, size_t ws_size,
                              hipStream_t stream)
{
    const float* Y_Win  = (const float*)d_in[0];
    const float* Y_bin  = (const float*)d_in[1];
    const float* Y_Whid = (const float*)d_in[2];
    const float* Y_bhid = (const float*)d_in[3];
    const float* Y_Wout = (const float*)d_in[4];
    const float* Y_bout = (const float*)d_in[5];
    const float* q_Win  = (const float*)d_in[6];
    const float* q_bin  = (const float*)d_in[7];
    const float* q_Whid = (const float*)d_in[8];
    const float* q_bhid = (const float*)d_in[9];
    const float* q_Wout = (const float*)d_in[10];
    const float* q_bout = (const float*)d_in[11];
    const float* y0p    = (const float*)d_in[12];
    const float* dW     = (const float*)d_in[13];

    float* ws = (float*)d_ws;   // 12800 (qgrid) + 12032 (frags) floats = 99,328 B

    hipMemsetAsync(d_out, 0, sizeof(float), stream);

    fbsnn_prep<<<dim3(101), dim3(256), 0, stream>>>(
        Y_Win, Y_bin, Y_Whid, Y_bhid, Y_Wout, Y_bout,
        q_Win, q_bin, q_Whid, q_bhid, q_Wout, q_bout, y0p, ws);

    fbsnn_main<<<dim3(NPATH / 16), dim3(1024), SMEM_BYTES, stream>>>(
        y0p, dW, ws, (float*)d_out);
}